// Round 14
// baseline (473.579 us; speedup 1.0000x reference)
//
#include <hip/hip_runtime.h>
#include <hip/hip_bf16.h>

#define D_EMB 128
#define T_HIST 200
#define T_PAD 208
#define NG 6400      // f32x4 granules per batch row
#define ITERS 64
#define NBLK 256
#define NSLOT 18     // 18 ring slots x 8KB (16 rows) = 147456 B

typedef float f32x4 __attribute__((ext_vector_type(4)));
typedef short bf16x8 __attribute__((ext_vector_type(8)));

__device__ __forceinline__ short f2bf(float f) {
    unsigned u = __builtin_bit_cast(unsigned, f);
    u += 0x7fffu + ((u >> 16) & 1u);
    return (short)(u >> 16);
}

// proven DPP 16-lane-group sum
__device__ __forceinline__ float dpp_reduce16(float x) {
    int v = __builtin_bit_cast(int, x);
    x += __builtin_bit_cast(float, __builtin_amdgcn_update_dpp(0, v, 0xB1, 0xF, 0xF, true));
    v = __builtin_bit_cast(int, x);
    x += __builtin_bit_cast(float, __builtin_amdgcn_update_dpp(0, v, 0x4E, 0xF, 0xF, true));
    v = __builtin_bit_cast(int, x);
    x += __builtin_bit_cast(float, __builtin_amdgcn_update_dpp(0, v, 0x141, 0xF, 0xF, true));
    v = __builtin_bit_cast(int, x);
    x += __builtin_bit_cast(float, __builtin_amdgcn_update_dpp(0, v, 0x140, 0xF, 0xF, true));
    return x;
}

// LDS-publish barrier (R13-proven form)
__device__ __forceinline__ void wg_barrier() {
    asm volatile("s_waitcnt lgkmcnt(0)");
    __builtin_amdgcn_s_barrier();
}

// async global->LDS (T3/T4 mechanism): per-lane global src, wave-uniform LDS
// base (+lane*width implicit). vmcnt-counted; stays in flight across s_barrier.
__device__ __forceinline__ void gl16(const void* g, void* l) {
    __builtin_amdgcn_global_load_lds(
        (const __attribute__((address_space(1))) void*)g,
        (__attribute__((address_space(3))) void*)l, 16, 0, 0);
}
__device__ __forceinline__ void gl4(const void* g, void* l) {
    __builtin_amdgcn_global_load_lds(
        (const __attribute__((address_space(1))) void*)g,
        (__attribute__((address_space(3))) void*)l, 4, 0, 0);
}

__global__ void pack_w_kernel(const float* __restrict__ W, short* __restrict__ wfrag) {
    int tid = blockIdx.x * blockDim.x + threadIdx.x;
    int fragid = tid >> 6;
    int lane = tid & 63;
    int ks = fragid >> 3;
    int nt = fragid & 7;
    int n = nt * 16 + (lane & 15);
    int k0 = ks * 32 + (lane >> 4) * 8;
    bf16x8 r;
#pragma unroll
    for (int j = 0; j < 8; ++j) r[j] = f2bf(W[(k0 + j) * D_EMB + n]);
    ((bf16x8*)wfrag)[fragid * 64 + lane] = r;
}

__global__ void tw_kernel(const float* __restrict__ target, const float* __restrict__ W,
                          const float* __restrict__ bias, float* __restrict__ TW) {
    int e = threadIdx.x;
    int b0 = blockIdx.x * 8;
    float bv = bias[e];
    float acc[8];
#pragma unroll
    for (int i = 0; i < 8; ++i) acc[i] = bv;
    for (int d = 0; d < D_EMB; ++d) {
        float wv = W[d * D_EMB + e];
#pragma unroll
        for (int i = 0; i < 8; ++i)
            acc[i] = fmaf(target[(size_t)(b0 + i) * D_EMB + d], wv, acc[i]);
    }
#pragma unroll
    for (int i = 0; i < 8; ++i) TW[(size_t)(b0 + i) * D_EMB + e] = acc[i];
}

// global_load_lds pipelined kernel. hist tile = 13 chunks x 16 rows (8 KB) in
// an 18-slot LDS ring, f32 (pass2 exact; MFMA A via proven elementwise f2bf).
// Steady queue per wave (14 ops/body, unconditional): at body(i) MFMA phase
// [TW(i),C0..C4(i)] + [C5..C12(i),TW(i+1),C0..C4(i+1)] in flight; counted
// waits vmcnt(15)/11/6 (= definite ops issued after C3/C7/C12). Loads cross
// barriers; HBM demand continuous.
__launch_bounds__(512, 2)
__global__ void attn_main(const float* __restrict__ hist,
                          const float* __restrict__ TW,
                          const float* __restrict__ q,
                          const short* __restrict__ wfrag,
                          float* __restrict__ out) {
    __shared__ __align__(16) f32x4 h4[NSLOT * 512];  // 147456 B
    __shared__ float s_twrep[2][512];                // 4096 B (per-wave TW replicas)
    __shared__ float s_logits[2][T_PAD];             // 1664 B
    __shared__ float s_scores[T_PAD];                // 832 B
    __shared__ float s_red[16];                      // 64 B
    __shared__ float s_p2[16][D_EMB];                // 8192 B  (total 162304 B)

    const int tid = threadIdx.x;
    const int l = tid & 63;
    const int w = tid >> 6;
    const int p = w & 3;
    const int hf = w >> 2;
    const int l15 = l & 15;
    const int lg = l >> 4;
    const f32x4 vzero = {0.f, 0.f, 0.f, 0.f};

    // gather offset within a 16-row chunk: phys granule tid holds logical
    // (row tid>>5, col (tid&31)^((tid>>5)&7))  [R1/R5-proven swizzle]
    const int gg = (tid >> 5) * 32 + ((tid & 31) ^ ((tid >> 5) & 7));
    // chunk 12 holds rows 192..199 real + 8 dup rows (clamped; finite, score-0)
    const int gg12 = (tid < 256) ? gg : (gg & 255);
    const int twoff = hf * 64 + l;  // wave w's TW replica = cols it reads

    bf16x8 Bf[4][4];
#pragma unroll
    for (int ks = 0; ks < 4; ++ks)
#pragma unroll
        for (int j = 0; j < 4; ++j)
            Bf[ks][j] = ((const bf16x8*)wfrag)[(ks * 8 + hf * 4 + j) * 64 + l];

    float qv[4];
#pragma unroll
    for (int j = 0; j < 4; ++j) qv[j] = q[hf * 64 + j * 16 + l15];

    const int base = blockIdx.x * ITERS;
    const f32x4* gh = (const f32x4*)hist;

    // ---- prologue: prime queue as [TW0, C0-4(0), C5-12(0), TW1, C0-4(1)] ----
    {
        const f32x4* g0 = gh + (size_t)base * NG;
        gl4(TW + (size_t)base * D_EMB + twoff, &s_twrep[0][w * 64]);
#pragma unroll
        for (int c = 0; c < 12; ++c) gl16(g0 + c * 512 + gg, h4 + c * 512 + w * 64);
        gl16(g0 + 12 * 512 + gg12, h4 + 12 * 512 + w * 64);
        const f32x4* g1 = gh + (size_t)(base + 1) * NG;
        gl4(TW + (size_t)(base + 1) * D_EMB + twoff, &s_twrep[1][w * 64]);
#pragma unroll
        for (int c = 0; c < 5; ++c) gl16(g1 + c * 512 + gg, h4 + (13 + c) * 512 + w * 64);
    }

    int sbase = 0;  // ring slot of current tile's chunk 0

    for (int i = 0; i < ITERS; ++i) {
        const int b = base + i;
        const int par = i & 1;

        // ===== MFMA phase: 3 vmcnt-counted groups (mts {0-3},{4-7},{8-12}) =====
        asm volatile("s_waitcnt vmcnt(15)");   // C0..C3(i) + TW(i) landed
        __builtin_amdgcn_s_barrier();
        __builtin_amdgcn_sched_barrier(0);

        float twv[4];
#pragma unroll
        for (int j = 0; j < 4; ++j) twv[j] = s_twrep[par][w * 64 + j * 16 + l15];

        auto do_mt = [&](int mt) {
            int slot = sbase + mt; if (slot >= NSLOT) slot -= NSLOT;
            const f32x4* hp = h4 + slot * 512 + l15 * 32;
            const int sw = l15 & 7;
            f32x4 acc[4];
#pragma unroll
            for (int j = 0; j < 4; ++j) acc[j] = vzero;
#pragma unroll
            for (int ks = 0; ks < 4; ++ks) {
                int c0 = ks * 8 + lg * 2;
                f32x4 alo = hp[c0 ^ sw];
                f32x4 ahi = hp[(c0 + 1) ^ sw];
                bf16x8 A;
                A[0] = f2bf(alo[0]); A[1] = f2bf(alo[1]);
                A[2] = f2bf(alo[2]); A[3] = f2bf(alo[3]);
                A[4] = f2bf(ahi[0]); A[5] = f2bf(ahi[1]);
                A[6] = f2bf(ahi[2]); A[7] = f2bf(ahi[3]);
#pragma unroll
                for (int j = 0; j < 4; ++j)
                    acc[j] = __builtin_amdgcn_mfma_f32_16x16x32_bf16(A, Bf[ks][j], acc[j], 0, 0, 0);
            }
            float part[4] = {0.f, 0.f, 0.f, 0.f};
#pragma unroll
            for (int j = 0; j < 4; ++j) {
#pragma unroll
                for (int rr = 0; rr < 4; ++rr)
                    part[rr] += fmaxf(acc[j][rr] + twv[j], 0.f) * qv[j];
            }
#pragma unroll
            for (int rr = 0; rr < 4; ++rr) part[rr] = dpp_reduce16(part[rr]);
            if (l15 == 0) {
                int row = mt * 16 + lg * 4;
                f32x4 v;
#pragma unroll
                for (int rr = 0; rr < 4; ++rr)
                    v[rr] = (row + rr < T_HIST) ? part[rr] : -1e30f;
                *(f32x4*)&s_logits[hf][row] = v;
            }
        };

        do_mt(p);

        asm volatile("s_waitcnt vmcnt(11)");   // C4..C7(i) landed
        __builtin_amdgcn_s_barrier();
        __builtin_amdgcn_sched_barrier(0);
        do_mt(4 + p);

        asm volatile("s_waitcnt vmcnt(6)");    // C8..C12(i) landed; 6 stay in flight
        __builtin_amdgcn_s_barrier();
        __builtin_amdgcn_sched_barrier(0);
        do_mt(8 + p);
        if (p == 0) do_mt(12);

        wg_barrier();

        // ===== softmax over T =====
        float lv = (tid < T_PAD) ? (s_logits[0][tid] + s_logits[1][tid]) : -1e30f;
        float m = lv;
#pragma unroll
        for (int off = 32; off >= 1; off >>= 1)
            m = fmaxf(m, __shfl_xor(m, off, 64));
        if (l == 0) s_red[w] = m;
        wg_barrier();
        float M = s_red[0];
#pragma unroll
        for (int k = 1; k < 8; ++k) M = fmaxf(M, s_red[k]);
        float e = (tid < T_PAD) ? __expf(lv - M) : 0.f;
        if (tid < T_PAD) s_scores[tid] = e;
        float sm = e;
#pragma unroll
        for (int off = 32; off >= 1; off >>= 1)
            sm += __shfl_xor(sm, off, 64);
        if (l == 0) s_red[8 + w] = sm;
        wg_barrier();
        float S = s_red[8];
#pragma unroll
        for (int k = 9; k < 16; ++k) S += s_red[k];

        // ===== pass 2: exact f32 from LDS =====
        {
            const int cch = tid >> 5, ccl = tid & 31;
            f32x4 acc2 = vzero;
#pragma unroll
            for (int tt = 0; tt < 13; ++tt) {
                int t = cch * 13 + tt;
                float sc = s_scores[t];  // t>=200 -> 0 (dup rows are finite)
                int slot = sbase + (t >> 4); if (slot >= NSLOT) slot -= NSLOT;
                f32x4 hv = h4[slot * 512 + (t & 15) * 32 + (ccl ^ (t & 7))];
#pragma unroll
                for (int rr = 0; rr < 4; ++rr) acc2[rr] = fmaf(sc, hv[rr], acc2[rr]);
            }
            *(f32x4*)&s_p2[cch][ccl * 4] = acc2;
        }
        wg_barrier();
        if (tid < 128) {
            float o = 0.f;
#pragma unroll
            for (int k = 0; k < 16; ++k) o += s_p2[k][tid];
            out[(size_t)b * D_EMB + tid] = o / S;
        }

        // ===== issue burst (unconditional; epilogue clamps to tile 63) =====
        {
            const int b1 = base + ((i + 1 < ITERS) ? i + 1 : ITERS - 1);
            const int b2 = base + ((i + 2 < ITERS) ? i + 2 : ITERS - 1);
            const f32x4* t1 = gh + (size_t)b1 * NG;
#pragma unroll
            for (int c = 5; c < 12; ++c) {   // slots sbase+0..6 (tile i C0..C6, freed)
                int s = sbase + (c - 5); if (s >= NSLOT) s -= NSLOT;
                gl16(t1 + c * 512 + gg, h4 + s * 512 + w * 64);
            }
            {
                int s = sbase + 7; if (s >= NSLOT) s -= NSLOT;
                gl16(t1 + 12 * 512 + gg12, h4 + s * 512 + w * 64);
            }
            gl4(TW + (size_t)b2 * D_EMB + twoff, &s_twrep[par][w * 64]);
            const f32x4* t2 = gh + (size_t)b2 * NG;
#pragma unroll
            for (int c = 0; c < 5; ++c) {    // slots sbase+8..12 (tile i C8..C12, freed)
                int s = sbase + 8 + c; if (s >= NSLOT) s -= NSLOT;
                gl16(t2 + c * 512 + gg, h4 + s * 512 + w * 64);
            }
        }
        sbase += 13; if (sbase >= NSLOT) sbase -= NSLOT;
    }

    // drain outstanding LDS-destination loads before LDS dealloc at endpgm
    asm volatile("s_waitcnt vmcnt(0)");
}

extern "C" void kernel_launch(void* const* d_in, const int* in_sizes, int n_in,
                              void* d_out, int out_size, void* d_ws, size_t ws_size,
                              hipStream_t stream) {
    const float* target = (const float*)d_in[0];
    const float* hist   = (const float*)d_in[1];
    const float* Wk     = (const float*)d_in[2];
    const float* Wb     = (const float*)d_in[3];
    const float* qk     = (const float*)d_in[4];
    float* out = (float*)d_out;

    short* wfrag = (short*)d_ws;                   // 32 KB
    float* TW    = (float*)((char*)d_ws + 32768);  // 8 MB

    pack_w_kernel<<<dim3(8), dim3(256), 0, stream>>>(Wk, wfrag);
    tw_kernel<<<dim3(2048), dim3(128), 0, stream>>>(target, Wk, Wb, TW);
    attn_main<<<dim3(NBLK), dim3(512), 0, stream>>>(hist, TW, qk, wfrag, out);
}

// Round 17
// 444.415 us; speedup vs baseline: 1.0656x; 1.0656x over previous
//
#include <hip/hip_runtime.h>
#include <hip/hip_bf16.h>

#define D_EMB 128
#define T_HIST 200
#define T_PAD 208
#define NG 6400      // f32x4 granules per batch row
#define ITERS 64
#define NBLK 256

typedef float f32x4 __attribute__((ext_vector_type(4)));
typedef short bf16x8 __attribute__((ext_vector_type(8)));

__device__ __forceinline__ short f2bf(float f) {
    unsigned u = __builtin_bit_cast(unsigned, f);
    u += 0x7fffu + ((u >> 16) & 1u);
    return (short)(u >> 16);
}

// LDS-publish barrier (R10-proven)
__device__ __forceinline__ void wg_barrier() {
    asm volatile("s_waitcnt lgkmcnt(0)" ::: "memory");
    __builtin_amdgcn_s_barrier();
}

// proven DPP 16-lane-group sum
__device__ __forceinline__ float dpp_reduce16(float x) {
    int v = __builtin_bit_cast(int, x);
    x += __builtin_bit_cast(float, __builtin_amdgcn_update_dpp(0, v, 0xB1, 0xF, 0xF, true));
    v = __builtin_bit_cast(int, x);
    x += __builtin_bit_cast(float, __builtin_amdgcn_update_dpp(0, v, 0x4E, 0xF, 0xF, true));
    v = __builtin_bit_cast(int, x);
    x += __builtin_bit_cast(float, __builtin_amdgcn_update_dpp(0, v, 0x141, 0xF, 0xF, true));
    v = __builtin_bit_cast(int, x);
    x += __builtin_bit_cast(float, __builtin_amdgcn_update_dpp(0, v, 0x140, 0xF, 0xF, true));
    return x;
}

// f32x4 granule -> 4 packed RNE bf16 (8B)
__device__ __forceinline__ uint2 cvt_granule(f32x4 v) {
    uint2 r;
    asm("v_cvt_pk_bf16_f32 %0, %1, %2" : "=v"(r.x) : "v"(v[0]), "v"(v[1]));
    asm("v_cvt_pk_bf16_f32 %0, %1, %2" : "=v"(r.y) : "v"(v[2]), "v"(v[3]));
    return r;
}

__global__ void pack_w_kernel(const float* __restrict__ W, short* __restrict__ wfrag) {
    int tid = blockIdx.x * blockDim.x + threadIdx.x;
    int fragid = tid >> 6;
    int lane = tid & 63;
    int ks = fragid >> 3;
    int nt = fragid & 7;
    int n = nt * 16 + (lane & 15);
    int k0 = ks * 32 + (lane >> 4) * 8;
    bf16x8 r;
#pragma unroll
    for (int j = 0; j < 8; ++j) r[j] = f2bf(W[(k0 + j) * D_EMB + n]);
    ((bf16x8*)wfrag)[fragid * 64 + lane] = r;
}

__global__ void tw_kernel(const float* __restrict__ target, const float* __restrict__ W,
                          const float* __restrict__ bias, float* __restrict__ TW) {
    int e = threadIdx.x;
    int b0 = blockIdx.x * 8;
    float bv = bias[e];
    float acc[8];
#pragma unroll
    for (int i = 0; i < 8; ++i) acc[i] = bv;
    for (int d = 0; d < D_EMB; ++d) {
        float wv = W[d * D_EMB + e];
#pragma unroll
        for (int i = 0; i < 8; ++i)
            acc[i] = fmaf(target[(size_t)(b0 + i) * D_EMB + d], wv, acc[i]);
    }
#pragma unroll
    for (int i = 0; i < 8; ++i) TW[(size_t)(b0 + i) * D_EMB + e] = acc[i];
}

// R10 (365.95us, proven) + safe L2-prefetches of tile i+2 granules 8..12 in
// the three formerly-HBM-idle segments. R15/R16 crashes were an OOB in the
// granule-12 prefetch (index base_g+6144 is only valid for base_g<256; on the
// global-last row it read past the allocation). Fix: clamp that one address
// per-lane to granule 11 for upper threads (always in-bounds, harmless warm).
__launch_bounds__(512, 2)
__global__ void attn_main(const float* __restrict__ hist,
                          const float* __restrict__ TW,
                          const float* __restrict__ q,
                          const short* __restrict__ wfrag,
                          float* __restrict__ out) {
    __shared__ __align__(16) uint2 h2[2][T_PAD * 32];  // 2 x 53248 B bf16 tiles
    __shared__ float s_tw[2][D_EMB];
    __shared__ float s_logits[2][T_PAD];
    __shared__ float s_scores[T_PAD];
    __shared__ float s_red[16];
    __shared__ float s_p2[16][D_EMB];

    const int tid = threadIdx.x;
    const int l = tid & 63;
    const int w = tid >> 6;
    const int p = w & 3;
    const int hf = w >> 2;
    const int l15 = l & 15;
    const int lg = l >> 4;
    const int r = tid >> 5;
    const int cc = tid & 31;
    const int c_log = (((cc >> 1) ^ (r & 7)) << 1) | (cc & 1);
    const int base_g = r * 32 + c_log;  // + k*512 per k
    // granule-12 prefetch offset, clamped in-bounds for all lanes:
    const int pre12 = (tid < 256) ? 12 * 512 : 11 * 512;
    const f32x4 vzero = {0.f, 0.f, 0.f, 0.f};

    bf16x8 Bf[4][4];
#pragma unroll
    for (int ks = 0; ks < 4; ++ks)
#pragma unroll
        for (int j = 0; j < 4; ++j)
            Bf[ks][j] = ((const bf16x8*)wfrag)[(ks * 8 + hf * 4 + j) * 64 + l];

    float qv[4];
#pragma unroll
    for (int j = 0; j < 4; ++j) qv[j] = q[hf * 64 + j * 16 + l15];

    // zero pad rows (t=200..207 live at half-granules [6400,6656)) in both buffers
    if (tid >= 256) {
        h2[0][6144 + tid] = uint2{0u, 0u};
        h2[1][6144 + tid] = uint2{0u, 0u};
    }

    const int base = blockIdx.x * ITERS;
    const f32x4* ghist = (const f32x4*)hist;

    f32x4 stgA[13], stgB[13];
    float twA = 0.f, twB = 0.f;

    {   // prologue: load tile 0 + issue tile 1
        const f32x4* g0 = ghist + (size_t)base * NG + base_g;
#pragma unroll
        for (int k = 0; k < 12; ++k) stgA[k] = g0[k * 512];
        if (tid < 256) stgA[12] = g0[12 * 512];
        if (tid < 128) twA = TW[(size_t)base * D_EMB + tid];
        const f32x4* g1 = ghist + (size_t)(base + 1) * NG + base_g;
#pragma unroll
        for (int k = 0; k < 12; ++k) stgB[k] = g1[k * 512];
        if (tid < 256) stgB[12] = g1[12 * 512];
        if (tid < 128) twB = TW[(size_t)(base + 1) * D_EMB + tid];
    }
    {   // commit tile 0 -> h2[0]
        uint2* d = h2[0];
#pragma unroll
        for (int k = 0; k < 12; ++k) d[tid + k * 512] = cvt_granule(stgA[k]);
        if (tid < 256) d[tid + 12 * 512] = cvt_granule(stgA[12]);
        if (tid < 128) s_tw[0][tid] = twA;
    }
    wg_barrier();

#define BODY(PAR, STG_CUR, STG_OTH, TW_CUR, TW_OTH, II)                           \
    {                                                                             \
        const int bb = base + (II);                                               \
        /* prefetch target: tile II+2 (clamped at epilogue; refetch = L2 hit) */  \
        const f32x4* gpre = ghist +                                               \
            (size_t)(((II) + 2 < ITERS) ? (bb + 2) : (base + ITERS - 1)) * NG +   \
            base_g;                                                               \
        float twv[4];                                                             \
        _Pragma("unroll") for (int j = 0; j < 4; ++j)                             \
            twv[j] = s_tw[PAR][hf * 64 + j * 16 + l15];                           \
        const bf16x8* hp = (const bf16x8*)h2[PAR];                                \
        for (int mt = p; mt < 13; mt += 4) {                                      \
            f32x4 acc[4];                                                         \
            _Pragma("unroll") for (int j = 0; j < 4; ++j) acc[j] = vzero;         \
            _Pragma("unroll") for (int ks = 0; ks < 4; ++ks) {                    \
                bf16x8 A = hp[l15 * 16 + ((ks * 4 + lg) ^ (l15 & 7)) + mt * 256]; \
                _Pragma("unroll") for (int j = 0; j < 4; ++j)                     \
                    acc[j] = __builtin_amdgcn_mfma_f32_16x16x32_bf16(             \
                        A, Bf[ks][j], acc[j], 0, 0, 0);                           \
            }                                                                     \
            float part[4] = {0.f, 0.f, 0.f, 0.f};                                 \
            _Pragma("unroll") for (int j = 0; j < 4; ++j) {                       \
                _Pragma("unroll") for (int rr = 0; rr < 4; ++rr)                  \
                    part[rr] += fmaxf(acc[j][rr] + twv[j], 0.f) * qv[j];          \
            }                                                                     \
            _Pragma("unroll") for (int rr = 0; rr < 4; ++rr)                      \
                part[rr] = dpp_reduce16(part[rr]);                                \
            if (l15 == 0) {                                                       \
                int row = mt * 16 + lg * 4;                                       \
                f32x4 v;                                                          \
                _Pragma("unroll") for (int rr = 0; rr < 4; ++rr)                  \
                    v[rr] = (row + rr < T_HIST) ? part[rr] : -1e30f;              \
                *(f32x4*)&s_logits[hf][row] = v;                                  \
            }                                                                     \
        }                                                                         \
        /* commit tile II+1 into the other LDS buffer */                          \
        if ((II) + 1 < ITERS) {                                                   \
            uint2* d = h2[1 - (PAR)];                                             \
            _Pragma("unroll") for (int k = 0; k < 12; ++k)                        \
                d[tid + k * 512] = cvt_granule(STG_OTH[k]);                       \
            if (tid < 256) d[tid + 12 * 512] = cvt_granule(STG_OTH[12]);          \
            if (tid < 128) s_tw[1 - (PAR)][tid] = TW_OTH;                         \
        }                                                                         \
        wg_barrier();  /* B1 */                                                   \
        /* segment 1 prefetches (granules 8,9 of tile II+2) */                    \
        f32x4 pf0 = gpre[8 * 512];                                                \
        f32x4 pf1 = gpre[9 * 512];                                                \
        float lv = (tid < T_PAD) ? (s_logits[0][tid] + s_logits[1][tid]) : -1e30f;\
        float m = lv;                                                             \
        _Pragma("unroll") for (int off = 32; off >= 1; off >>= 1)                 \
            m = fmaxf(m, __shfl_xor(m, off, 64));                                 \
        if (l == 0) s_red[w] = m;                                                 \
        wg_barrier();  /* B2 */                                                   \
        asm volatile("" :: "v"(pf0), "v"(pf1));  /* keep-alive; wait is free */   \
        f32x4 pf2 = gpre[10 * 512];                                               \
        float M = s_red[0];                                                       \
        _Pragma("unroll") for (int k = 1; k < 8; ++k) M = fmaxf(M, s_red[k]);     \
        float e = (tid < T_PAD) ? __expf(lv - M) : 0.f;                           \
        if (tid < T_PAD) s_scores[tid] = e;                                       \
        float sm = e;                                                             \
        _Pragma("unroll") for (int off = 32; off >= 1; off >>= 1)                 \
            sm += __shfl_xor(sm, off, 64);                                        \
        if (l == 0) s_red[8 + w] = sm;                                            \
        wg_barrier();  /* B3 */                                                   \
        asm volatile("" :: "v"(pf2));                                             \
        f32x4 pf3 = gpre[11 * 512];                                               \
        f32x4 pf4 = gpre[pre12];  /* clamped: in-bounds for ALL lanes */          \
        float S = s_red[8];                                                       \
        _Pragma("unroll") for (int k = 9; k < 16; ++k) S += s_red[k];             \
        /* pass 2 from exact f32 registers (tile II) */                           \
        f32x4 acc2 = vzero;                                                       \
        _Pragma("unroll") for (int k = 0; k < 12; ++k) {                          \
            float sc = s_scores[r + 16 * k];                                      \
            _Pragma("unroll") for (int rr = 0; rr < 4; ++rr)                      \
                acc2[rr] = fmaf(sc, STG_CUR[k][rr], acc2[rr]);                    \
        }                                                                         \
        if (tid < 256) {                                                          \
            float sc = s_scores[r + 192];                                         \
            _Pragma("unroll") for (int rr = 0; rr < 4; ++rr)                      \
                acc2[rr] = fmaf(sc, STG_CUR[12][rr], acc2[rr]);                   \
        }                                                                         \
        *(f32x4*)&s_p2[r][c_log * 4] = acc2;                                      \
        wg_barrier();  /* B4 */                                                   \
        asm volatile("" :: "v"(pf3), "v"(pf4));                                   \
        if (tid < 128) {                                                          \
            float o = 0.f;                                                        \
            _Pragma("unroll") for (int k = 0; k < 16; ++k) o += s_p2[k][tid];     \
            out[(size_t)bb * D_EMB + tid] = o / S;                                \
        }                                                                         \
        /* issue real loads for tile II+2 (granules 8..12 now L2-hot) */          \
        if ((II) + 2 < ITERS) {                                                   \
            const f32x4* gn = ghist + (size_t)(bb + 2) * NG + base_g;             \
            _Pragma("unroll") for (int k = 0; k < 12; ++k) STG_CUR[k] = gn[k*512];\
            if (tid < 256) STG_CUR[12] = gn[12 * 512];                            \
            if (tid < 128) TW_CUR = TW[(size_t)(bb + 2) * D_EMB + tid];           \
        }                                                                         \
    }

    for (int ii = 0; ii < ITERS; ii += 2) {
        BODY(0, stgA, stgB, twA, twB, ii)
        BODY(1, stgB, stgA, twB, twA, ii + 1)
    }
#undef BODY
}

extern "C" void kernel_launch(void* const* d_in, const int* in_sizes, int n_in,
                              void* d_out, int out_size, void* d_ws, size_t ws_size,
                              hipStream_t stream) {
    const float* target = (const float*)d_in[0];
    const float* hist   = (const float*)d_in[1];
    const float* Wk     = (const float*)d_in[2];
    const float* Wb     = (const float*)d_in[3];
    const float* qk     = (const float*)d_in[4];
    float* out = (float*)d_out;

    short* wfrag = (short*)d_ws;                   // 32 KB
    float* TW    = (float*)((char*)d_ws + 32768);  // 8 MB

    pack_w_kernel<<<dim3(8), dim3(256), 0, stream>>>(Wk, wfrag);
    tw_kernel<<<dim3(2048), dim3(128), 0, stream>>>(target, Wk, Wb, TW);
    attn_main<<<dim3(NBLK), dim3(512), 0, stream>>>(hist, TW, qk, wfrag, out);
}

// Round 18
// 353.663 us; speedup vs baseline: 1.3391x; 1.2566x over previous
//
#include <hip/hip_runtime.h>
#include <hip/hip_bf16.h>

#define D_EMB 128
#define T_HIST 200
#define T_PAD 208
#define SLPAD 256    // padded logits row (entries 208..255 = -1e30)
#define NG 6400      // f32x4 granules per batch row
#define ITERS 64
#define NBLK 256

typedef float f32x4 __attribute__((ext_vector_type(4)));
typedef short bf16x8 __attribute__((ext_vector_type(8)));

__device__ __forceinline__ short f2bf(float f) {
    unsigned u = __builtin_bit_cast(unsigned, f);
    u += 0x7fffu + ((u >> 16) & 1u);
    return (short)(u >> 16);
}

// LDS-publish barrier (R10-proven)
__device__ __forceinline__ void wg_barrier() {
    asm volatile("s_waitcnt lgkmcnt(0)" ::: "memory");
    __builtin_amdgcn_s_barrier();
}

// proven DPP 16-lane-group sum
__device__ __forceinline__ float dpp_reduce16(float x) {
    int v = __builtin_bit_cast(int, x);
    x += __builtin_bit_cast(float, __builtin_amdgcn_update_dpp(0, v, 0xB1, 0xF, 0xF, true));
    v = __builtin_bit_cast(int, x);
    x += __builtin_bit_cast(float, __builtin_amdgcn_update_dpp(0, v, 0x4E, 0xF, 0xF, true));
    v = __builtin_bit_cast(int, x);
    x += __builtin_bit_cast(float, __builtin_amdgcn_update_dpp(0, v, 0x141, 0xF, 0xF, true));
    v = __builtin_bit_cast(int, x);
    x += __builtin_bit_cast(float, __builtin_amdgcn_update_dpp(0, v, 0x140, 0xF, 0xF, true));
    return x;
}

// f32x4 granule -> 4 packed RNE bf16 (8B)
__device__ __forceinline__ uint2 cvt_granule(f32x4 v) {
    uint2 r;
    asm("v_cvt_pk_bf16_f32 %0, %1, %2" : "=v"(r.x) : "v"(v[0]), "v"(v[1]));
    asm("v_cvt_pk_bf16_f32 %0, %1, %2" : "=v"(r.y) : "v"(v[2]), "v"(v[3]));
    return r;
}

__global__ void pack_w_kernel(const float* __restrict__ W, short* __restrict__ wfrag) {
    int tid = blockIdx.x * blockDim.x + threadIdx.x;
    int fragid = tid >> 6;
    int lane = tid & 63;
    int ks = fragid >> 3;
    int nt = fragid & 7;
    int n = nt * 16 + (lane & 15);
    int k0 = ks * 32 + (lane >> 4) * 8;
    bf16x8 r;
#pragma unroll
    for (int j = 0; j < 8; ++j) r[j] = f2bf(W[(k0 + j) * D_EMB + n]);
    ((bf16x8*)wfrag)[fragid * 64 + lane] = r;
}

__global__ void tw_kernel(const float* __restrict__ target, const float* __restrict__ W,
                          const float* __restrict__ bias, float* __restrict__ TW) {
    int e = threadIdx.x;
    int b0 = blockIdx.x * 8;
    float bv = bias[e];
    float acc[8];
#pragma unroll
    for (int i = 0; i < 8; ++i) acc[i] = bv;
    for (int d = 0; d < D_EMB; ++d) {
        float wv = W[d * D_EMB + e];
#pragma unroll
        for (int i = 0; i < 8; ++i)
            acc[i] = fmaf(target[(size_t)(b0 + i) * D_EMB + d], wv, acc[i]);
    }
#pragma unroll
    for (int i = 0; i < 8; ++i) TW[(size_t)(b0 + i) * D_EMB + e] = acc[i];
}

// R10 (365.95us proven) with the softmax's two barrier segments merged into
// ONE: waves 0-1 each redundantly compute the full 208-value max+sum entirely
// in-register (8 LDS reads + 12 shfl per thread; no s_red, no cross-wave
// reduce). Body barriers: 4 -> 3. All staging/MFMA/pass2 bytes identical.
__launch_bounds__(512, 2)
__global__ void attn_main(const float* __restrict__ hist,
                          const float* __restrict__ TW,
                          const float* __restrict__ q,
                          const short* __restrict__ wfrag,
                          float* __restrict__ out) {
    __shared__ __align__(16) uint2 h2[2][T_PAD * 32];  // 2 x 53248 B bf16 tiles
    __shared__ float s_tw[2][D_EMB];
    __shared__ float s_logits[2][SLPAD];  // [208,256) = -1e30 pad
    __shared__ float s_scores[T_PAD];
    __shared__ float s_p2[16][D_EMB];

    const int tid = threadIdx.x;
    const int l = tid & 63;
    const int w = tid >> 6;
    const int p = w & 3;
    const int hf = w >> 2;
    const int l15 = l & 15;
    const int lg = l >> 4;
    const int r = tid >> 5;
    const int cc = tid & 31;
    const int c_log = (((cc >> 1) ^ (r & 7)) << 1) | (cc & 1);
    const int base_g = r * 32 + c_log;  // + k*512 per k
    const f32x4 vzero = {0.f, 0.f, 0.f, 0.f};

    bf16x8 Bf[4][4];
#pragma unroll
    for (int ks = 0; ks < 4; ++ks)
#pragma unroll
        for (int j = 0; j < 4; ++j)
            Bf[ks][j] = ((const bf16x8*)wfrag)[(ks * 8 + hf * 4 + j) * 64 + l];

    float qv[4];
#pragma unroll
    for (int j = 0; j < 4; ++j) qv[j] = q[hf * 64 + j * 16 + l15];

    // zero pad rows (t=200..207 live at half-granules [6400,6656)) in both buffers
    if (tid >= 256) {
        h2[0][6144 + tid] = uint2{0u, 0u};
        h2[1][6144 + tid] = uint2{0u, 0u};
    }
    // -inf pad for logit slots [208,256) once (never rewritten: MFMA writes <208)
    if (tid < 96) s_logits[tid / 48][208 + (tid % 48)] = -1e30f;

    const int base = blockIdx.x * ITERS;
    const f32x4* ghist = (const f32x4*)hist;

    f32x4 stgA[13], stgB[13];
    float twA = 0.f, twB = 0.f;

    {   // prologue: load tile 0 + issue tile 1
        const f32x4* g0 = ghist + (size_t)base * NG + base_g;
#pragma unroll
        for (int k = 0; k < 12; ++k) stgA[k] = g0[k * 512];
        if (tid < 256) stgA[12] = g0[12 * 512];
        if (tid < 128) twA = TW[(size_t)base * D_EMB + tid];
        const f32x4* g1 = ghist + (size_t)(base + 1) * NG + base_g;
#pragma unroll
        for (int k = 0; k < 12; ++k) stgB[k] = g1[k * 512];
        if (tid < 256) stgB[12] = g1[12 * 512];
        if (tid < 128) twB = TW[(size_t)(base + 1) * D_EMB + tid];
    }
    {   // commit tile 0 -> h2[0]
        uint2* d = h2[0];
#pragma unroll
        for (int k = 0; k < 12; ++k) d[tid + k * 512] = cvt_granule(stgA[k]);
        if (tid < 256) d[tid + 12 * 512] = cvt_granule(stgA[12]);
        if (tid < 128) s_tw[0][tid] = twA;
    }
    wg_barrier();

#define BODY(PAR, STG_CUR, STG_OTH, TW_CUR, TW_OTH, II)                           \
    {                                                                             \
        const int bb = base + (II);                                               \
        float twv[4];                                                             \
        _Pragma("unroll") for (int j = 0; j < 4; ++j)                             \
            twv[j] = s_tw[PAR][hf * 64 + j * 16 + l15];                           \
        const bf16x8* hp = (const bf16x8*)h2[PAR];                                \
        for (int mt = p; mt < 13; mt += 4) {                                      \
            f32x4 acc[4];                                                         \
            _Pragma("unroll") for (int j = 0; j < 4; ++j) acc[j] = vzero;         \
            _Pragma("unroll") for (int ks = 0; ks < 4; ++ks) {                    \
                bf16x8 A = hp[l15 * 16 + ((ks * 4 + lg) ^ (l15 & 7)) + mt * 256]; \
                _Pragma("unroll") for (int j = 0; j < 4; ++j)                     \
                    acc[j] = __builtin_amdgcn_mfma_f32_16x16x32_bf16(             \
                        A, Bf[ks][j], acc[j], 0, 0, 0);                           \
            }                                                                     \
            float part[4] = {0.f, 0.f, 0.f, 0.f};                                 \
            _Pragma("unroll") for (int j = 0; j < 4; ++j) {                       \
                _Pragma("unroll") for (int rr = 0; rr < 4; ++rr)                  \
                    part[rr] += fmaxf(acc[j][rr] + twv[j], 0.f) * qv[j];          \
            }                                                                     \
            _Pragma("unroll") for (int rr = 0; rr < 4; ++rr)                      \
                part[rr] = dpp_reduce16(part[rr]);                                \
            if (l15 == 0) {                                                       \
                int row = mt * 16 + lg * 4;                                       \
                f32x4 v;                                                          \
                _Pragma("unroll") for (int rr = 0; rr < 4; ++rr)                  \
                    v[rr] = (row + rr < T_HIST) ? part[rr] : -1e30f;              \
                *(f32x4*)&s_logits[hf][row] = v;                                  \
            }                                                                     \
        }                                                                         \
        /* commit tile II+1 into the other LDS buffer (R10 position) */           \
        if ((II) + 1 < ITERS) {                                                   \
            uint2* d = h2[1 - (PAR)];                                             \
            _Pragma("unroll") for (int k = 0; k < 12; ++k)                        \
                d[tid + k * 512] = cvt_granule(STG_OTH[k]);                       \
            if (tid < 256) d[tid + 12 * 512] = cvt_granule(STG_OTH[12]);          \
            if (tid < 128) s_tw[1 - (PAR)][tid] = TW_OTH;                         \
        }                                                                         \
        wg_barrier();  /* B1: publishes s_logits + h2[1-PAR] */                   \
        /* single-segment softmax: waves 0,1 each do the FULL 208 reduction */    \
        float S = 0.f;                                                            \
        if (tid < 128) {                                                          \
            float lv0 = s_logits[0][l]       + s_logits[1][l];                    \
            float lv1 = s_logits[0][l + 64]  + s_logits[1][l + 64];               \
            float lv2 = s_logits[0][l + 128] + s_logits[1][l + 128];              \
            float lv3 = s_logits[0][l + 192] + s_logits[1][l + 192];              \
            float mx = fmaxf(fmaxf(lv0, lv1), fmaxf(lv2, lv3));                   \
            _Pragma("unroll") for (int off = 32; off >= 1; off >>= 1)             \
                mx = fmaxf(mx, __shfl_xor(mx, off, 64));                          \
            float e0 = __expf(lv0 - mx), e1 = __expf(lv1 - mx);                   \
            float e2 = __expf(lv2 - mx), e3 = __expf(lv3 - mx);                   \
            float s4 = (e0 + e1) + (e2 + e3);                                     \
            _Pragma("unroll") for (int off = 32; off >= 1; off >>= 1)             \
                s4 += __shfl_xor(s4, off, 64);                                    \
            S = s4;                                                               \
            if (w == 0) {                                                         \
                s_scores[l] = e0; s_scores[l + 64] = e1; s_scores[l + 128] = e2;  \
                if (l < 16) s_scores[l + 192] = e3;                               \
            }                                                                     \
        }                                                                         \
        wg_barrier();  /* B2: publishes s_scores */                               \
        /* pass 2 from exact f32 registers (tile II) */                           \
        f32x4 acc2 = vzero;                                                       \
        _Pragma("unroll") for (int k = 0; k < 12; ++k) {                          \
            float sc = s_scores[r + 16 * k];                                      \
            _Pragma("unroll") for (int rr = 0; rr < 4; ++rr)                      \
                acc2[rr] = fmaf(sc, STG_CUR[k][rr], acc2[rr]);                    \
        }                                                                         \
        if (tid < 256) {                                                          \
            float sc = s_scores[r + 192];                                         \
            _Pragma("unroll") for (int rr = 0; rr < 4; ++rr)                      \
                acc2[rr] = fmaf(sc, STG_CUR[12][rr], acc2[rr]);                   \
        }                                                                         \
        *(f32x4*)&s_p2[r][c_log * 4] = acc2;                                      \
        wg_barrier();  /* B3: publishes s_p2 */                                   \
        /* issue loads for tile II+2 first (max runway), then out */              \
        if ((II) + 2 < ITERS) {                                                   \
            const f32x4* gn = ghist + (size_t)(bb + 2) * NG + base_g;             \
            _Pragma("unroll") for (int k = 0; k < 12; ++k) STG_CUR[k] = gn[k*512];\
            if (tid < 256) STG_CUR[12] = gn[12 * 512];                            \
            if (tid < 128) TW_CUR = TW[(size_t)(bb + 2) * D_EMB + tid];           \
        }                                                                         \
        if (tid < 128) {                                                          \
            float o = 0.f;                                                        \
            _Pragma("unroll") for (int k = 0; k < 16; ++k) o += s_p2[k][tid];     \
            out[(size_t)bb * D_EMB + tid] = o / S;                                \
        }                                                                         \
    }

    for (int ii = 0; ii < ITERS; ii += 2) {
        BODY(0, stgA, stgB, twA, twB, ii)
        BODY(1, stgB, stgA, twB, twA, ii + 1)
    }
#undef BODY
}

extern "C" void kernel_launch(void* const* d_in, const int* in_sizes, int n_in,
                              void* d_out, int out_size, void* d_ws, size_t ws_size,
                              hipStream_t stream) {
    const float* target = (const float*)d_in[0];
    const float* hist   = (const float*)d_in[1];
    const float* Wk     = (const float*)d_in[2];
    const float* Wb     = (const float*)d_in[3];
    const float* qk     = (const float*)d_in[4];
    float* out = (float*)d_out;

    short* wfrag = (short*)d_ws;                   // 32 KB
    float* TW    = (float*)((char*)d_ws + 32768);  // 8 MB

    pack_w_kernel<<<dim3(8), dim3(256), 0, stream>>>(Wk, wfrag);
    tw_kernel<<<dim3(2048), dim3(128), 0, stream>>>(target, Wk, Wb, TW);
    attn_main<<<dim3(NBLK), dim3(512), 0, stream>>>(hist, TW, qk, wfrag, out);
}